// Round 3
// baseline (492.683 us; speedup 1.0000x reference)
//
#include <hip/hip_runtime.h>

#define C 16
#define NIMG 24
#define H 96
#define W 192
#define PX (H*W)            // 18432
#define LOG2E 1.44269504088896f

// workspace float offsets
#define QP_OFF 0
#define KP_OFF (NIMG*PX*2)                      // 884736
#define VP_OFF (2*NIMG*PX*2)                    // 1769472
#define X1_OFF (VP_OFF + NIMG*PX*C)             // 8847360
#define CMAX_OFF (X1_OFF + NIMG*C*PX)           // 15925248
#define RMAX_OFF (CMAX_OFF + NIMG*2*W)          // +9216
// total ~15939072 floats (~63.8 MB)

__global__ __launch_bounds__(256)
void qkv_kernel(const float* __restrict__ x, long xn_s, long xc_s,
                const float* __restrict__ qw, const float* __restrict__ qb,
                const float* __restrict__ kw, const float* __restrict__ kb,
                const float* __restrict__ vw, const float* __restrict__ vb,
                float2* __restrict__ Qp, float2* __restrict__ Kp,
                float4* __restrict__ Vp)
{
    __shared__ float wq[2*C+2], wk[2*C+2], wv[C*C+C];
    int tid = threadIdx.x;
    if (tid < 2*C) { wq[tid] = qw[tid]; wk[tid] = kw[tid]; }
    if (tid < 2)   { wq[2*C+tid] = qb[tid]; wk[2*C+tid] = kb[tid]; }
    if (tid < C*C) wv[tid] = vw[tid];
    if (tid < C)   wv[C*C+tid] = vb[tid];
    __syncthreads();

    int id = blockIdx.x*256 + tid;        // 0 .. 442367
    int n  = id / PX;
    int p  = id - n*PX;
    const float* xp = x + (long)n*xn_s + p;

    float xv[C];
    #pragma unroll
    for (int c = 0; c < C; c++) xv[c] = xp[(long)c*xc_s];

    float q0 = wq[2*C], q1 = wq[2*C+1];
    float k0 = wk[2*C], k1 = wk[2*C+1];
    #pragma unroll
    for (int c = 0; c < C; c++) {
        q0 += wq[c]*xv[c];   q1 += wq[C+c]*xv[c];
        k0 += wk[c]*xv[c];   k1 += wk[C+c]*xv[c];
    }
    Qp[id] = make_float2(q0, q1);
    Kp[id] = make_float2(k0, k1);

    float vv[C];
    #pragma unroll
    for (int o = 0; o < C; o++) {
        float a = wv[C*C+o];
        #pragma unroll
        for (int c = 0; c < C; c++) a += wv[o*C+c]*xv[c];
        vv[o] = a;
    }
    long vbase = (long)id * 4;
    Vp[vbase+0] = make_float4(vv[0],  vv[1],  vv[2],  vv[3]);
    Vp[vbase+1] = make_float4(vv[4],  vv[5],  vv[6],  vv[7]);
    Vp[vbase+2] = make_float4(vv[8],  vv[9],  vv[10], vv[11]);
    Vp[vbase+3] = make_float4(vv[12], vv[13], vv[14], vv[15]);
}

// per-image column/row |K| maxima (for the softmax shift bound)
__global__ __launch_bounds__(192)
void stats_kernel(const float2* __restrict__ Kp,
                  float* __restrict__ cmax, float* __restrict__ rmax)
{
    int n = blockIdx.x;
    int tid = threadIdx.x;
    const float2* Kpn = Kp + n*PX;

    float c0 = 0.f, c1 = 0.f;
    for (int h = 0; h < H; h++) {
        float2 k = Kpn[h*W + tid];
        c0 = fmaxf(c0, fabsf(k.x));
        c1 = fmaxf(c1, fabsf(k.y));
    }
    cmax[n*2*W + tid]     = c0;
    cmax[n*2*W + W + tid] = c1;

    if (tid < H) {
        float r0 = 0.f, r1 = 0.f;
        for (int j = 0; j < W; j++) {
            float2 k = Kpn[tid*W + j];
            r0 = fmaxf(r0, fabsf(k.x));
            r1 = fmaxf(r1, fabsf(k.y));
        }
        rmax[n*2*H + tid]     = r0;
        rmax[n*2*H + H + tid] = r1;
    }
}

__global__ __launch_bounds__(192)
void attn_kernel(const float2* __restrict__ Qp, const float2* __restrict__ Kp,
                 const float4* __restrict__ Vp,
                 const float* __restrict__ cmax, const float* __restrict__ rmax,
                 const float* __restrict__ xres, long xn_s, long xc_s,
                 float* __restrict__ out, long on_s, long oc_s,
                 const float* __restrict__ gamma_p)
{
    int bid = blockIdx.x;          // 0 .. NIMG*H-1
    int n   = bid / H;
    int h0  = bid - n*H;
    int w   = threadIdx.x;         // 0..191

    const float2* Qpn = Qp + n*PX;
    const float2* Kpn = Kp + n*PX;
    const float4* Vpn = Vp + (long)n*PX*4;

    // q (log2 domain) and softmax shift bound m
    float c0 = cmax[n*2*W + w], c1 = cmax[n*2*W + W + w];
    float2 qq = Qpn[h0*W + w];
    float qx = qq.x * LOG2E;
    float qy = qq.y * LOG2E;
    float aq0 = fabsf(qx), aq1 = fabsf(qy);
    float r0 = rmax[n*2*H + h0], r1 = rmax[n*2*H + H + h0];
    float m = fmaxf(aq0*c0 + aq1*c1, aq0*r0 + aq1*r1);

    float s = 0.f;
    float acc[C] = {};

    // ---- column (H) part: coalesced reads, diag masked ----
    #pragma unroll 2
    for (int j = 0; j < H; j++) {
        float2 k = Kpn[j*W + w];
        int vb = (j*W + w)*4;
        float4 v0 = Vpn[vb+0], v1 = Vpn[vb+1], v2 = Vpn[vb+2], v3 = Vpn[vb+3];
        float e = qx*k.x + qy*k.y;
        float p = __builtin_amdgcn_exp2f(e - m);
        p = (j == h0) ? 0.0f : p;
        s += p;
        acc[0]  += p*v0.x; acc[1]  += p*v0.y; acc[2]  += p*v0.z; acc[3]  += p*v0.w;
        acc[4]  += p*v1.x; acc[5]  += p*v1.y; acc[6]  += p*v1.z; acc[7]  += p*v1.w;
        acc[8]  += p*v2.x; acc[9]  += p*v2.y; acc[10] += p*v2.z; acc[11] += p*v2.w;
        acc[12] += p*v3.x; acc[13] += p*v3.y; acc[14] += p*v3.z; acc[15] += p*v3.w;
    }

    // ---- row (W) part: wave-uniform broadcast reads, unmasked ----
    {
        const float2* kr = Kpn + h0*W;
        const float4* vr = Vpn + (long)h0*W*4;
        #pragma unroll 2
        for (int j = 0; j < W; j++) {
            float2 k = kr[j];
            float e = qx*k.x + qy*k.y;
            float p = __builtin_amdgcn_exp2f(e - m);
            s += p;
            float4 v0 = vr[j*4+0], v1 = vr[j*4+1], v2 = vr[j*4+2], v3 = vr[j*4+3];
            acc[0]  += p*v0.x; acc[1]  += p*v0.y; acc[2]  += p*v0.z; acc[3]  += p*v0.w;
            acc[4]  += p*v1.x; acc[5]  += p*v1.y; acc[6]  += p*v1.z; acc[7]  += p*v1.w;
            acc[8]  += p*v2.x; acc[9]  += p*v2.y; acc[10] += p*v2.z; acc[11] += p*v2.w;
            acc[12] += p*v3.x; acc[13] += p*v3.y; acc[14] += p*v3.z; acc[15] += p*v3.w;
        }
    }

    // ---- epilogue: gamma*(acc/s) + residual ----
    float g = gamma_p[0];
    float inv = 1.0f / s;
    #pragma unroll
    for (int c = 0; c < C; c++) {
        float res = g*(acc[c]*inv)
                  + xres[(long)n*xn_s + (long)c*xc_s + h0*W + w];
        out[(long)n*on_s + (long)c*oc_s + h0*W + w] = res;
    }
}

extern "C" void kernel_launch(void* const* d_in, const int* in_sizes, int n_in,
                              void* d_out, int out_size, void* d_ws, size_t ws_size,
                              hipStream_t stream) {
    const float* cost = (const float*)d_in[0];   // (1,16,24,96,192)
    const float* q_w  = (const float*)d_in[1];
    const float* q_b  = (const float*)d_in[2];
    const float* k_w  = (const float*)d_in[3];
    const float* k_b  = (const float*)d_in[4];
    const float* v_w  = (const float*)d_in[5];
    const float* v_b  = (const float*)d_in[6];
    const float* gamma= (const float*)d_in[7];
    float* out = (float*)d_out;
    float* ws  = (float*)d_ws;

    float2* Qp = (float2*)(ws + QP_OFF);
    float2* Kp = (float2*)(ws + KP_OFF);
    float4* Vp = (float4*)(ws + VP_OFF);
    float*  X1 = ws + X1_OFF;
    float*  cm = ws + CMAX_OFF;
    float*  rm = ws + RMAX_OFF;

    const int qkv_blocks  = (NIMG*PX)/256;   // 1728
    const int attn_blocks = NIMG*H;          // 2304

    // pass 1: x = cost_volume, layout [c][n][h][w] (n stride PX, c stride 24*PX)
    qkv_kernel<<<qkv_blocks, 256, 0, stream>>>(
        cost, (long)PX, (long)NIMG*PX,
        q_w, q_b, k_w, k_b, v_w, v_b, Qp, Kp, Vp);
    stats_kernel<<<NIMG, 192, 0, stream>>>(Kp, cm, rm);
    attn_kernel<<<attn_blocks, 192, 0, stream>>>(
        Qp, Kp, Vp, cm, rm,
        cost, (long)PX, (long)NIMG*PX,
        X1, (long)C*PX, (long)PX,
        gamma);

    // pass 2: x = X1 ([n][c][h][w]); final out layout [c][n][h][w]
    qkv_kernel<<<qkv_blocks, 256, 0, stream>>>(
        X1, (long)C*PX, (long)PX,
        q_w, q_b, k_w, k_b, v_w, v_b, Qp, Kp, Vp);
    stats_kernel<<<NIMG, 192, 0, stream>>>(Kp, cm, rm);
    attn_kernel<<<attn_blocks, 192, 0, stream>>>(
        Qp, Kp, Vp, cm, rm,
        X1, (long)C*PX, (long)PX,
        out, (long)PX, (long)NIMG*PX,
        gamma);
}

// Round 4
// 345.109 us; speedup vs baseline: 1.4276x; 1.4276x over previous
//
#include <hip/hip_runtime.h>

#define C 16
#define NIMG 24
#define H 96
#define W 192
#define PX (H*W)            // 18432
#define ROWS 2
#define LOG2E 1.44269504088896f

// workspace float offsets
#define QP_OFF 0                                // float2 [n][px]
#define KP_OFF (NIMG*PX*2)                      // float2 [n][px]
#define VP_OFF (2*NIMG*PX*2)                    // float4 [n][4][px] (4 ch per float4)
#define X1_OFF (VP_OFF + NIMG*PX*C)             // 8847360
#define CMAX_OFF (X1_OFF + NIMG*C*PX)           // 15925248
#define RMAX_OFF (CMAX_OFF + NIMG*2*W)          // +9216

__global__ __launch_bounds__(256)
void qkv_kernel(const float* __restrict__ x, long xn_s, long xc_s,
                const float* __restrict__ qw, const float* __restrict__ qb,
                const float* __restrict__ kw, const float* __restrict__ kb,
                const float* __restrict__ vw, const float* __restrict__ vb,
                float2* __restrict__ Qp, float2* __restrict__ Kp,
                float4* __restrict__ Vp)
{
    __shared__ float wq[2*C+2], wk[2*C+2], wv[C*C+C];
    int tid = threadIdx.x;
    if (tid < 2*C) { wq[tid] = qw[tid]; wk[tid] = kw[tid]; }
    if (tid < 2)   { wq[2*C+tid] = qb[tid]; wk[2*C+tid] = kb[tid]; }
    if (tid < C*C) wv[tid] = vw[tid];
    if (tid < C)   wv[C*C+tid] = vb[tid];
    __syncthreads();

    int id = blockIdx.x*256 + tid;        // 0 .. 442367
    int n  = id / PX;
    int p  = id - n*PX;
    const float* xp = x + (long)n*xn_s + p;

    float xv[C];
    #pragma unroll
    for (int c = 0; c < C; c++) xv[c] = xp[(long)c*xc_s];

    float q0 = wq[2*C], q1 = wq[2*C+1];
    float k0 = wk[2*C], k1 = wk[2*C+1];
    #pragma unroll
    for (int c = 0; c < C; c++) {
        q0 += wq[c]*xv[c];   q1 += wq[C+c]*xv[c];
        k0 += wk[c]*xv[c];   k1 += wk[C+c]*xv[c];
    }
    Qp[id] = make_float2(q0, q1);
    Kp[id] = make_float2(k0, k1);

    float vv[C];
    #pragma unroll
    for (int o = 0; o < C; o++) {
        float a = wv[C*C+o];
        #pragma unroll
        for (int c = 0; c < C; c++) a += wv[o*C+c]*xv[c];
        vv[o] = a;
    }
    // channel-group-major: V[n][c4][px], float4 = channels 4c4..4c4+3 of pixel p
    #pragma unroll
    for (int c4 = 0; c4 < 4; c4++)
        Vp[((long)n*4 + c4)*PX + p] =
            make_float4(vv[c4*4+0], vv[c4*4+1], vv[c4*4+2], vv[c4*4+3]);
}

// per-image column/row |K| maxima (for the softmax shift bound)
__global__ __launch_bounds__(192)
void stats_kernel(const float2* __restrict__ Kp,
                  float* __restrict__ cmax, float* __restrict__ rmax)
{
    int n = blockIdx.x;
    int tid = threadIdx.x;
    const float2* Kpn = Kp + n*PX;

    float c0 = 0.f, c1 = 0.f;
    for (int h = 0; h < H; h++) {
        float2 k = Kpn[h*W + tid];
        c0 = fmaxf(c0, fabsf(k.x));
        c1 = fmaxf(c1, fabsf(k.y));
    }
    cmax[n*2*W + tid]     = c0;
    cmax[n*2*W + W + tid] = c1;

    if (tid < H) {
        float r0 = 0.f, r1 = 0.f;
        for (int j = 0; j < W; j++) {
            float2 k = Kpn[tid*W + j];
            r0 = fmaxf(r0, fabsf(k.x));
            r1 = fmaxf(r1, fabsf(k.y));
        }
        rmax[n*2*H + tid]     = r0;
        rmax[n*2*H + H + tid] = r1;
    }
}

__global__ __launch_bounds__(192)
void attn_kernel(const float2* __restrict__ Qp, const float2* __restrict__ Kp,
                 const float4* __restrict__ Vp,
                 const float* __restrict__ cmax, const float* __restrict__ rmax,
                 const float* __restrict__ xres, long xn_s, long xc_s,
                 float* __restrict__ out, long on_s, long oc_s,
                 const float* __restrict__ gamma_p)
{
    // bijective XCD swizzle: nwg = NIMG*(H/ROWS) = 1152, divisible by 8
    const int chunk = (NIMG*(H/ROWS)) / 8;
    int bid = blockIdx.x;
    int swz = (bid & 7)*chunk + (bid >> 3);
    int n   = swz / (H/ROWS);
    int h0  = (swz - n*(H/ROWS)) * ROWS;
    int w   = threadIdx.x;         // 0..191

    const float2* Qpn = Qp + n*PX;
    const float2* Kpn = Kp + n*PX;
    const float4* Vpn = Vp + (long)n*4*PX;

    // q (log2 domain) and softmax shift bound m
    float c0 = cmax[n*2*W + w], c1 = cmax[n*2*W + W + w];
    float qx[ROWS], qy[ROWS], m[ROWS];
    #pragma unroll
    for (int r = 0; r < ROWS; r++) {
        float2 qq = Qpn[(h0+r)*W + w];
        qx[r] = qq.x * LOG2E;
        qy[r] = qq.y * LOG2E;
        float aq0 = fabsf(qx[r]), aq1 = fabsf(qy[r]);
        float r0 = rmax[n*2*H + h0+r], r1 = rmax[n*2*H + H + h0+r];
        m[r] = fmaxf(aq0*c0 + aq1*c1, aq0*r0 + aq1*r1);
    }

    float s[ROWS] = {};
    float acc[ROWS][C] = {};

    // ---- column (H) part: fully coalesced reads, diag masked ----
    #pragma unroll 2
    for (int j = 0; j < H; j++) {
        float2 k  = Kpn[j*W + w];
        int    p0 = j*W + w;
        float4 v0 = Vpn[0*PX + p0];
        float4 v1 = Vpn[1*PX + p0];
        float4 v2 = Vpn[2*PX + p0];
        float4 v3 = Vpn[3*PX + p0];
        #pragma unroll
        for (int r = 0; r < ROWS; r++) {
            float e = qx[r]*k.x + qy[r]*k.y;
            float p = __builtin_amdgcn_exp2f(e - m[r]);
            p = (j == h0 + r) ? 0.0f : p;
            s[r] += p;
            acc[r][0]  += p*v0.x; acc[r][1]  += p*v0.y; acc[r][2]  += p*v0.z; acc[r][3]  += p*v0.w;
            acc[r][4]  += p*v1.x; acc[r][5]  += p*v1.y; acc[r][6]  += p*v1.z; acc[r][7]  += p*v1.w;
            acc[r][8]  += p*v2.x; acc[r][9]  += p*v2.y; acc[r][10] += p*v2.z; acc[r][11] += p*v2.w;
            acc[r][12] += p*v3.x; acc[r][13] += p*v3.y; acc[r][14] += p*v3.z; acc[r][15] += p*v3.w;
        }
    }

    // ---- row (W) part: wave-uniform broadcast reads, unmasked ----
    #pragma unroll
    for (int r = 0; r < ROWS; r++) {
        const float2* kr  = Kpn + (h0+r)*W;
        const float4* vr0 = Vpn + 0*PX + (h0+r)*W;
        const float4* vr1 = Vpn + 1*PX + (h0+r)*W;
        const float4* vr2 = Vpn + 2*PX + (h0+r)*W;
        const float4* vr3 = Vpn + 3*PX + (h0+r)*W;
        float sr = s[r];
        float qxr = qx[r], qyr = qy[r], mr = m[r];
        #pragma unroll 2
        for (int j = 0; j < W; j++) {
            float2 k = kr[j];
            float e = qxr*k.x + qyr*k.y;
            float p = __builtin_amdgcn_exp2f(e - mr);
            sr += p;
            float4 v0 = vr0[j], v1 = vr1[j], v2 = vr2[j], v3 = vr3[j];
            acc[r][0]  += p*v0.x; acc[r][1]  += p*v0.y; acc[r][2]  += p*v0.z; acc[r][3]  += p*v0.w;
            acc[r][4]  += p*v1.x; acc[r][5]  += p*v1.y; acc[r][6]  += p*v1.z; acc[r][7]  += p*v1.w;
            acc[r][8]  += p*v2.x; acc[r][9]  += p*v2.y; acc[r][10] += p*v2.z; acc[r][11] += p*v2.w;
            acc[r][12] += p*v3.x; acc[r][13] += p*v3.y; acc[r][14] += p*v3.z; acc[r][15] += p*v3.w;
        }
        s[r] = sr;
    }

    // ---- epilogue: gamma*(acc/s) + residual ----
    float g = gamma_p[0];
    #pragma unroll
    for (int r = 0; r < ROWS; r++) {
        float inv = 1.0f / s[r];
        #pragma unroll
        for (int c = 0; c < C; c++) {
            float res = g*(acc[r][c]*inv)
                      + xres[(long)n*xn_s + (long)c*xc_s + (h0+r)*W + w];
            out[(long)n*on_s + (long)c*oc_s + (h0+r)*W + w] = res;
        }
    }
}

extern "C" void kernel_launch(void* const* d_in, const int* in_sizes, int n_in,
                              void* d_out, int out_size, void* d_ws, size_t ws_size,
                              hipStream_t stream) {
    const float* cost = (const float*)d_in[0];   // (1,16,24,96,192)
    const float* q_w  = (const float*)d_in[1];
    const float* q_b  = (const float*)d_in[2];
    const float* k_w  = (const float*)d_in[3];
    const float* k_b  = (const float*)d_in[4];
    const float* v_w  = (const float*)d_in[5];
    const float* v_b  = (const float*)d_in[6];
    const float* gamma= (const float*)d_in[7];
    float* out = (float*)d_out;
    float* ws  = (float*)d_ws;

    float2* Qp = (float2*)(ws + QP_OFF);
    float2* Kp = (float2*)(ws + KP_OFF);
    float4* Vp = (float4*)(ws + VP_OFF);
    float*  X1 = ws + X1_OFF;
    float*  cm = ws + CMAX_OFF;
    float*  rm = ws + RMAX_OFF;

    const int qkv_blocks  = (NIMG*PX)/256;   // 1728
    const int attn_blocks = NIMG*(H/ROWS);   // 1152

    // pass 1: x = cost_volume, layout [c][n][h][w] (n stride PX, c stride 24*PX)
    qkv_kernel<<<qkv_blocks, 256, 0, stream>>>(
        cost, (long)PX, (long)NIMG*PX,
        q_w, q_b, k_w, k_b, v_w, v_b, Qp, Kp, Vp);
    stats_kernel<<<NIMG, 192, 0, stream>>>(Kp, cm, rm);
    attn_kernel<<<attn_blocks, 192, 0, stream>>>(
        Qp, Kp, Vp, cm, rm,
        cost, (long)PX, (long)NIMG*PX,
        X1, (long)C*PX, (long)PX,
        gamma);

    // pass 2: x = X1 ([n][c][h][w]); final out layout [c][n][h][w]
    qkv_kernel<<<qkv_blocks, 256, 0, stream>>>(
        X1, (long)C*PX, (long)PX,
        q_w, q_b, k_w, k_b, v_w, v_b, Qp, Kp, Vp);
    stats_kernel<<<NIMG, 192, 0, stream>>>(Kp, cm, rm);
    attn_kernel<<<attn_blocks, 192, 0, stream>>>(
        Qp, Kp, Vp, cm, rm,
        X1, (long)C*PX, (long)PX,
        out, (long)PX, (long)NIMG*PX,
        gamma);
}

// Round 6
// 338.912 us; speedup vs baseline: 1.4537x; 1.0183x over previous
//
#include <hip/hip_runtime.h>

#define C 16
#define NIMG 24
#define H 96
#define W 192
#define PX (H*W)            // 18432
#define LOG2E 1.44269504088896f

typedef float v2f __attribute__((ext_vector_type(2)));
typedef float v4f __attribute__((ext_vector_type(4)));

// workspace float offsets
#define QP_OFF 0                                // float2 [n][px]
#define KP_OFF (NIMG*PX*2)                      // float2 [n][px]
#define VP_OFF (2*NIMG*PX*2)                    // float4 [n][4][px] (4 ch per float4)
#define X1_OFF (VP_OFF + NIMG*PX*C)             // 8847360
#define CMAX_OFF (X1_OFF + NIMG*C*PX)           // 15925248
#define RMAX_OFF (CMAX_OFF + NIMG*2*W)          // +9216

__global__ __launch_bounds__(256)
void qkv_kernel(const float* __restrict__ x, long xn_s, long xc_s,
                const float* __restrict__ qw, const float* __restrict__ qb,
                const float* __restrict__ kw, const float* __restrict__ kb,
                const float* __restrict__ vw, const float* __restrict__ vb,
                float2* __restrict__ Qp, float2* __restrict__ Kp,
                float4* __restrict__ Vp)
{
    __shared__ float wq[2*C+2], wk[2*C+2], wv[C*C+C];
    int tid = threadIdx.x;
    if (tid < 2*C) { wq[tid] = qw[tid]; wk[tid] = kw[tid]; }
    if (tid < 2)   { wq[2*C+tid] = qb[tid]; wk[2*C+tid] = kb[tid]; }
    if (tid < C*C) wv[tid] = vw[tid];
    if (tid < C)   wv[C*C+tid] = vb[tid];
    __syncthreads();

    int id = blockIdx.x*256 + tid;        // 0 .. 442367
    int n  = id / PX;
    int p  = id - n*PX;
    const float* xp = x + (long)n*xn_s + p;

    float xv[C];
    #pragma unroll
    for (int c = 0; c < C; c++) xv[c] = xp[(long)c*xc_s];

    float q0 = wq[2*C], q1 = wq[2*C+1];
    float k0 = wk[2*C], k1 = wk[2*C+1];
    #pragma unroll
    for (int c = 0; c < C; c++) {
        q0 += wq[c]*xv[c];   q1 += wq[C+c]*xv[c];
        k0 += wk[c]*xv[c];   k1 += wk[C+c]*xv[c];
    }
    Qp[id] = make_float2(q0, q1);
    Kp[id] = make_float2(k0, k1);

    float vv[C];
    #pragma unroll
    for (int o = 0; o < C; o++) {
        float a = wv[C*C+o];
        #pragma unroll
        for (int c = 0; c < C; c++) a += wv[o*C+c]*xv[c];
        vv[o] = a;
    }
    #pragma unroll
    for (int c4 = 0; c4 < 4; c4++)
        Vp[((long)n*4 + c4)*PX + p] =
            make_float4(vv[c4*4+0], vv[c4*4+1], vv[c4*4+2], vv[c4*4+3]);
}

__global__ __launch_bounds__(192)
void stats_kernel(const float2* __restrict__ Kp,
                  float* __restrict__ cmax, float* __restrict__ rmax)
{
    int n = blockIdx.x;
    int tid = threadIdx.x;
    const float2* Kpn = Kp + n*PX;

    float c0 = 0.f, c1 = 0.f;
    for (int h = 0; h < H; h++) {
        float2 k = Kpn[h*W + tid];
        c0 = fmaxf(c0, fabsf(k.x));
        c1 = fmaxf(c1, fabsf(k.y));
    }
    cmax[n*2*W + tid]     = c0;
    cmax[n*2*W + W + tid] = c1;

    if (tid < H) {
        float r0 = 0.f, r1 = 0.f;
        for (int j = 0; j < W; j++) {
            float2 k = Kpn[tid*W + j];
            r0 = fmaxf(r0, fabsf(k.x));
            r1 = fmaxf(r1, fabsf(k.y));
        }
        rmax[n*2*H + tid]     = r0;
        rmax[n*2*H + H + tid] = r1;
    }
}

#define PKFMA(a, vv, pp) asm("v_pk_fma_f32 %0, %1, %2, %0" : "+v"(a) : "v"(vv), "v"(pp))

#define ACCUM8(A, pp) do { \
    v2f va = {v0.x, v0.y}, vb = {v0.z, v0.w}; \
    v2f vc = {v1.x, v1.y}, vd = {v1.z, v1.w}; \
    v2f ve = {v2.x, v2.y}, vf = {v2.z, v2.w}; \
    v2f vg = {v3.x, v3.y}, vh = {v3.z, v3.w}; \
    PKFMA(A[0], va, pp); PKFMA(A[1], vb, pp); \
    PKFMA(A[2], vc, pp); PKFMA(A[3], vd, pp); \
    PKFMA(A[4], ve, pp); PKFMA(A[5], vf, pp); \
    PKFMA(A[6], vg, pp); PKFMA(A[7], vh, pp); \
} while (0)

__global__ __launch_bounds__(384, 7)
void attn_kernel(const float2* __restrict__ Qp, const float2* __restrict__ Kp,
                 const v4f* __restrict__ Vp,
                 const float* __restrict__ cmax, const float* __restrict__ rmax,
                 const float* __restrict__ xres, long xn_s, long xc_s,
                 float* __restrict__ out, long on_s, long oc_s,
                 const float* __restrict__ gamma_p)
{
    // merge slab: [slot r][17 = 16 acc + s][w]; stride-1 in w -> conflict-free
    __shared__ float lds[2][17][192];

    // bijective XCD swizzle: nwg = NIMG*(H/2) = 1152, divisible by 8
    const int chunk = (NIMG*(H/2)) / 8;
    int bid = blockIdx.x;
    int swz = (bid & 7)*chunk + (bid >> 3);
    int n   = swz / (H/2);
    int h0  = (swz - n*(H/2)) * 2;
    int tid = threadIdx.x;
    int grp = (tid >= 192) ? 1 : 0;     // 0: col+rowtail waves, 1: row-main waves
    int w   = tid - grp*192;            // 0..191

    const float2* Qpn = Qp + n*PX;
    const float2* Kpn = Kp + n*PX;
    const v4f*    Vpn = Vp + (long)n*4*PX;

    // q (log2 domain) and softmax shift bound m, both rows
    float c0 = cmax[n*2*W + w], c1 = cmax[n*2*W + W + w];
    float qx[2], qy[2], m[2];
    #pragma unroll
    for (int r = 0; r < 2; r++) {
        float2 qq = Qpn[(h0+r)*W + w];
        qx[r] = qq.x * LOG2E;
        qy[r] = qq.y * LOG2E;
        float aq0 = fabsf(qx[r]), aq1 = fabsf(qy[r]);
        float r0 = rmax[n*2*H + h0+r], r1 = rmax[n*2*H + H + h0+r];
        m[r] = fmaxf(aq0*c0 + aq1*c1, aq0*r0 + aq1*r1);
    }

    v2f acc0[8], acc1[8];
    #pragma unroll
    for (int i = 0; i < 8; i++) { acc0[i] = (v2f){0.f,0.f}; acc1[i] = (v2f){0.f,0.f}; }
    float s0 = 0.f, s1 = 0.f;

    if (grp == 0) {
        // ---- column part: j in [0,H), both rows, coalesced loads, diag masked ----
        #pragma unroll 2
        for (int j = 0; j < H; j++) {
            float2 k  = Kpn[j*W + w];
            int    p0 = j*W + w;
            v4f v0 = Vpn[0*PX + p0];
            v4f v1 = Vpn[1*PX + p0];
            v4f v2 = Vpn[2*PX + p0];
            v4f v3 = Vpn[3*PX + p0];
            {
                float e = qx[0]*k.x + qy[0]*k.y;
                float p = __builtin_amdgcn_exp2f(e - m[0]);
                p = (j == h0) ? 0.0f : p;
                s0 += p;
                v2f pp = {p, p};
                ACCUM8(acc0, pp);
            }
            {
                float e = qx[1]*k.x + qy[1]*k.y;
                float p = __builtin_amdgcn_exp2f(e - m[1]);
                p = (j == h0+1) ? 0.0f : p;
                s1 += p;
                v2f pp = {p, p};
                ACCUM8(acc1, pp);
            }
        }
        // ---- row tail: j in [144,W), both rows, uniform loads ----
        #pragma unroll
        for (int r = 0; r < 2; r++) {
            const float2* kr  = Kpn + (h0+r)*W;
            const v4f* vr0 = Vpn + 0*PX + (h0+r)*W;
            const v4f* vr1 = Vpn + 1*PX + (h0+r)*W;
            const v4f* vr2 = Vpn + 2*PX + (h0+r)*W;
            const v4f* vr3 = Vpn + 3*PX + (h0+r)*W;
            float qxr = qx[r], qyr = qy[r], mr = m[r];
            #pragma unroll 2
            for (int j = 144; j < W; j++) {
                float2 k = kr[j];
                float e = qxr*k.x + qyr*k.y;
                float p = __builtin_amdgcn_exp2f(e - mr);
                v2f pp = {p, p};
                v4f v0 = vr0[j], v1 = vr1[j], v2 = vr2[j], v3 = vr3[j];
                if (r == 0) { s0 += p; ACCUM8(acc0, pp); }
                else        { s1 += p; ACCUM8(acc1, pp); }
            }
        }
        // publish r=1 partial (group 1 finalizes row h0+1)
        #pragma unroll
        for (int c = 0; c < C; c++) lds[1][c][w] = acc1[c>>1][c&1];
        lds[1][16][w] = s1;
    } else {
        // ---- row main: j in [0,144), both rows, uniform loads ----
        #pragma unroll
        for (int r = 0; r < 2; r++) {
            const float2* kr  = Kpn + (h0+r)*W;
            const v4f* vr0 = Vpn + 0*PX + (h0+r)*W;
            const v4f* vr1 = Vpn + 1*PX + (h0+r)*W;
            const v4f* vr2 = Vpn + 2*PX + (h0+r)*W;
            const v4f* vr3 = Vpn + 3*PX + (h0+r)*W;
            float qxr = qx[r], qyr = qy[r], mr = m[r];
            #pragma unroll 2
            for (int j = 0; j < 144; j++) {
                float2 k = kr[j];
                float e = qxr*k.x + qyr*k.y;
                float p = __builtin_amdgcn_exp2f(e - mr);
                v2f pp = {p, p};
                v4f v0 = vr0[j], v1 = vr1[j], v2 = vr2[j], v3 = vr3[j];
                if (r == 0) { s0 += p; ACCUM8(acc0, pp); }
                else        { s1 += p; ACCUM8(acc1, pp); }
            }
        }
        // publish r=0 partial (group 0 finalizes row h0)
        #pragma unroll
        for (int c = 0; c < C; c++) lds[0][c][w] = acc0[c>>1][c&1];
        lds[0][16][w] = s0;
    }

    __syncthreads();

    // ---- finalize: group g handles row h0+g ----
    float g = gamma_p[0];
    if (grp == 0) {
        float st = s0 + lds[0][16][w];
        float inv = 1.0f / st;
        #pragma unroll
        for (int c = 0; c < C; c++) {
            float tot = acc0[c>>1][c&1] + lds[0][c][w];
            float res = g*(tot*inv)
                      + xres[(long)n*xn_s + (long)c*xc_s + h0*W + w];
            out[(long)n*on_s + (long)c*oc_s + h0*W + w] = res;
        }
    } else {
        float st = s1 + lds[1][16][w];
        float inv = 1.0f / st;
        #pragma unroll
        for (int c = 0; c < C; c++) {
            float tot = acc1[c>>1][c&1] + lds[1][c][w];
            float res = g*(tot*inv)
                      + xres[(long)n*xn_s + (long)c*xc_s + (h0+1)*W + w];
            out[(long)n*on_s + (long)c*oc_s + (h0+1)*W + w] = res;
        }
    }
}

extern "C" void kernel_launch(void* const* d_in, const int* in_sizes, int n_in,
                              void* d_out, int out_size, void* d_ws, size_t ws_size,
                              hipStream_t stream) {
    const float* cost = (const float*)d_in[0];   // (1,16,24,96,192)
    const float* q_w  = (const float*)d_in[1];
    const float* q_b  = (const float*)d_in[2];
    const float* k_w  = (const float*)d_in[3];
    const float* k_b  = (const float*)d_in[4];
    const float* v_w  = (const float*)d_in[5];
    const float* v_b  = (const float*)d_in[6];
    const float* gamma= (const float*)d_in[7];
    float* out = (float*)d_out;
    float* ws  = (float*)d_ws;

    float2* Qp = (float2*)(ws + QP_OFF);
    float2* Kp = (float2*)(ws + KP_OFF);
    float4* Vp = (float4*)(ws + VP_OFF);
    float*  X1 = ws + X1_OFF;
    float*  cm = ws + CMAX_OFF;
    float*  rm = ws + RMAX_OFF;

    const int qkv_blocks  = (NIMG*PX)/256;   // 1728
    const int attn_blocks = NIMG*(H/2);      // 1152

    // pass 1: x = cost_volume, layout [c][n][h][w] (n stride PX, c stride 24*PX)
    qkv_kernel<<<qkv_blocks, 256, 0, stream>>>(
        cost, (long)PX, (long)NIMG*PX,
        q_w, q_b, k_w, k_b, v_w, v_b, Qp, Kp, Vp);
    stats_kernel<<<NIMG, 192, 0, stream>>>(Kp, cm, rm);
    attn_kernel<<<attn_blocks, 384, 0, stream>>>(
        Qp, Kp, (const v4f*)Vp, cm, rm,
        cost, (long)PX, (long)NIMG*PX,
        X1, (long)C*PX, (long)PX,
        gamma);

    // pass 2: x = X1 ([n][c][h][w]); final out layout [c][n][h][w]
    qkv_kernel<<<qkv_blocks, 256, 0, stream>>>(
        X1, (long)C*PX, (long)PX,
        q_w, q_b, k_w, k_b, v_w, v_b, Qp, Kp, Vp);
    stats_kernel<<<NIMG, 192, 0, stream>>>(Kp, cm, rm);
    attn_kernel<<<attn_blocks, 384, 0, stream>>>(
        Qp, Kp, (const v4f*)Vp, cm, rm,
        X1, (long)C*PX, (long)PX,
        out, (long)PX, (long)NIMG*PX,
        gamma);
}

// Round 8
// 333.532 us; speedup vs baseline: 1.4772x; 1.0161x over previous
//
#include <hip/hip_runtime.h>

#define C 16
#define NIMG 24
#define H 96
#define W 192
#define PX (H*W)            // 18432
#define LOG2E 1.44269504088896f

typedef float v4f __attribute__((ext_vector_type(4)));

// workspace float offsets
#define QP_OFF 0                                // float2 [n][px]
#define KP_OFF (NIMG*PX*2)                      // float2 [n][px]
#define VP_OFF (2*NIMG*PX*2)                    // v4f [n][h][c4][w]
#define X1_OFF (VP_OFF + NIMG*PX*C)             // 8847360
#define CMAX_OFF (X1_OFF + NIMG*C*PX)           // 15925248
#define RMAX_OFF (CMAX_OFF + NIMG*2*W)          // +9216

__global__ __launch_bounds__(256)
void qkv_kernel(const float* __restrict__ x, long xn_s, long xc_s,
                const float* __restrict__ qw, const float* __restrict__ qb,
                const float* __restrict__ kw, const float* __restrict__ kb,
                const float* __restrict__ vw, const float* __restrict__ vb,
                float2* __restrict__ Qp, float2* __restrict__ Kp,
                float4* __restrict__ Vp)
{
    __shared__ float wq[2*C+2], wk[2*C+2], wv[C*C+C];
    int tid = threadIdx.x;
    if (tid < 2*C) { wq[tid] = qw[tid]; wk[tid] = kw[tid]; }
    if (tid < 2)   { wq[2*C+tid] = qb[tid]; wk[2*C+tid] = kb[tid]; }
    if (tid < C*C) wv[tid] = vw[tid];
    if (tid < C)   wv[C*C+tid] = vb[tid];
    __syncthreads();

    int id = blockIdx.x*256 + tid;        // 0 .. 442367
    int n  = id / PX;
    int p  = id - n*PX;
    int h  = p / W;
    int w  = p - h*W;
    const float* xp = x + (long)n*xn_s + p;

    float xv[C];
    #pragma unroll
    for (int c = 0; c < C; c++) xv[c] = xp[(long)c*xc_s];

    float q0 = wq[2*C], q1 = wq[2*C+1];
    float k0 = wk[2*C], k1 = wk[2*C+1];
    #pragma unroll
    for (int c = 0; c < C; c++) {
        q0 += wq[c]*xv[c];   q1 += wq[C+c]*xv[c];
        k0 += wk[c]*xv[c];   k1 += wk[C+c]*xv[c];
    }
    Qp[id] = make_float2(q0, q1);
    Kp[id] = make_float2(k0, k1);

    float vv[C];
    #pragma unroll
    for (int o = 0; o < C; o++) {
        float a = wv[C*C+o];
        #pragma unroll
        for (int c = 0; c < C; c++) a += wv[o*C+c]*xv[c];
        vv[o] = a;
    }
    // layout: V[n][h][c4][w], float4 = channels 4c4..4c4+3 of pixel (h,w)
    #pragma unroll
    for (int c4 = 0; c4 < 4; c4++)
        Vp[(((long)n*H + h)*4 + c4)*W + w] =
            make_float4(vv[c4*4+0], vv[c4*4+1], vv[c4*4+2], vv[c4*4+3]);
}

__global__ __launch_bounds__(192)
void stats_kernel(const float2* __restrict__ Kp,
                  float* __restrict__ cmax, float* __restrict__ rmax)
{
    int n = blockIdx.x;
    int tid = threadIdx.x;
    const float2* Kpn = Kp + n*PX;

    float c0 = 0.f, c1 = 0.f;
    for (int h = 0; h < H; h++) {
        float2 k = Kpn[h*W + tid];
        c0 = fmaxf(c0, fabsf(k.x));
        c1 = fmaxf(c1, fabsf(k.y));
    }
    cmax[n*2*W + tid]     = c0;
    cmax[n*2*W + W + tid] = c1;

    if (tid < H) {
        float r0 = 0.f, r1 = 0.f;
        for (int j = 0; j < W; j++) {
            float2 k = Kpn[tid*W + j];
            r0 = fmaxf(r0, fabsf(k.x));
            r1 = fmaxf(r1, fabsf(k.y));
        }
        rmax[n*2*H + tid]     = r0;
        rmax[n*2*H + H + tid] = r1;
    }
}

__global__ __launch_bounds__(384, 7)
void attn_kernel(const float2* __restrict__ Qp, const float2* __restrict__ Kp,
                 const v4f* __restrict__ Vp,
                 const float* __restrict__ cmax, const float* __restrict__ rmax,
                 const float* __restrict__ xres, long xn_s, long xc_s,
                 float* __restrict__ out, long on_s, long oc_s,
                 const float* __restrict__ gamma_p)
{
    // row slab: [r][j][20]: V ch 0..15 at [0..15], K at [16],[17], pad [18..19]
    // stride 20 floats (80 B) keeps v4f writes 16B-aligned.
    __shared__ float slab[2][W][20];   // 30720 B

    // bijective XCD swizzle: nwg = NIMG*(H/2) = 1152, divisible by 8
    const int chunk = (NIMG*(H/2)) / 8;
    int bid = blockIdx.x;
    int swz = (bid & 7)*chunk + (bid >> 3);
    int n   = swz / (H/2);
    int h0  = (swz - n*(H/2)) * 2;
    int tid = threadIdx.x;
    int r   = tid / 192;               // wave-uniform (3 waves per r)
    int w   = tid - r*192;             // 0..191
    int hr  = h0 + r;

    const float2* Qpn = Qp + n*PX;
    const float2* Kpn = Kp + n*PX;
    const v4f*    Vpn = Vp + (long)n*PX*4;   // [h][c4][w]

    // ---- stage own row's V and K into LDS (coalesced over w) ----
    #pragma unroll
    for (int c4 = 0; c4 < 4; c4++) {
        v4f v = Vpn[((long)hr*4 + c4)*W + w];
        *(v4f*)&slab[r][w][c4*4] = v;
    }
    {
        float2 k2 = Kpn[hr*W + w];
        *(float2*)&slab[r][w][16] = k2;
    }

    // q (log2 domain) and softmax shift bound m (own row only)
    float c0 = cmax[n*2*W + w], c1 = cmax[n*2*W + W + w];
    float2 qq = Qpn[hr*W + w];
    float qx = qq.x * LOG2E;
    float qy = qq.y * LOG2E;
    float aq0 = fabsf(qx), aq1 = fabsf(qy);
    float r0 = rmax[n*2*H + hr], r1 = rmax[n*2*H + H + hr];
    float m = fmaxf(aq0*c0 + aq1*c1, aq0*r0 + aq1*r1);

    v4f acc[4] = {};
    float s = 0.f;

    __syncthreads();

    // ---- column (H) part: coalesced global, carried pointers, diag masked ----
    {
        const float2* kp = Kpn + w;
        const v4f*    vp = Vpn + w;
        #pragma unroll 2
        for (int j = 0; j < H; j++) {
            float2 k = *kp;
            v4f a0 = vp[0*W], a1 = vp[1*W], a2 = vp[2*W], a3 = vp[3*W];
            float e = qx*k.x + qy*k.y;
            float p = __builtin_amdgcn_exp2f(e - m);
            p = (j == hr) ? 0.0f : p;
            s += p;
            acc[0] += a0 * p;
            acc[1] += a1 * p;
            acc[2] += a2 * p;
            acc[3] += a3 * p;
            kp += W;
            vp += 4*W;
        }
    }

    // ---- row (W) part: uniform LDS broadcast, imm offsets, unmasked ----
    {
        const float* sp = &slab[r][0][0];
        #pragma unroll 8
        for (int j = 0; j < W; j++) {
            const float* pj = sp + j*20;
            v4f a0 = *(const v4f*)(pj + 0);
            v4f a1 = *(const v4f*)(pj + 4);
            v4f a2 = *(const v4f*)(pj + 8);
            v4f a3 = *(const v4f*)(pj + 12);
            float kx = pj[16], ky = pj[17];
            float e = qx*kx + qy*ky;
            float p = __builtin_amdgcn_exp2f(e - m);
            s += p;
            acc[0] += a0 * p;
            acc[1] += a1 * p;
            acc[2] += a2 * p;
            acc[3] += a3 * p;
        }
    }

    // ---- epilogue: gamma*(acc/s) + residual; thread owns row hr ----
    float g = gamma_p[0];
    float inv = 1.0f / s;
    #pragma unroll
    for (int c = 0; c < C; c++) {
        float tot = acc[c>>2][c&3];
        float res = g*(tot*inv)
                  + xres[(long)n*xn_s + (long)c*xc_s + hr*W + w];
        out[(long)n*on_s + (long)c*oc_s + hr*W + w] = res;
    }
}

extern "C" void kernel_launch(void* const* d_in, const int* in_sizes, int n_in,
                              void* d_out, int out_size, void* d_ws, size_t ws_size,
                              hipStream_t stream) {
    const float* cost = (const float*)d_in[0];   // (1,16,24,96,192)
    const float* q_w  = (const float*)d_in[1];
    const float* q_b  = (const float*)d_in[2];
    const float* k_w  = (const float*)d_in[3];
    const float* k_b  = (const float*)d_in[4];
    const float* v_w  = (const float*)d_in[5];
    const float* v_b  = (const float*)d_in[6];
    const float* gamma= (const float*)d_in[7];
    float* out = (float*)d_out;
    float* ws  = (float*)d_ws;

    float2* Qp = (float2*)(ws + QP_OFF);
    float2* Kp = (float2*)(ws + KP_OFF);
    float4* Vp = (float4*)(ws + VP_OFF);
    float*  X1 = ws + X1_OFF;
    float*  cm = ws + CMAX_OFF;
    float*  rm = ws + RMAX_OFF;

    const int qkv_blocks  = (NIMG*PX)/256;   // 1728
    const int attn_blocks = NIMG*(H/2);      // 1152

    // pass 1: x = cost_volume, layout [c][n][h][w] (n stride PX, c stride 24*PX)
    qkv_kernel<<<qkv_blocks, 256, 0, stream>>>(
        cost, (long)PX, (long)NIMG*PX,
        q_w, q_b, k_w, k_b, v_w, v_b, Qp, Kp, Vp);
    stats_kernel<<<NIMG, 192, 0, stream>>>(Kp, cm, rm);
    attn_kernel<<<attn_blocks, 384, 0, stream>>>(
        Qp, Kp, (const v4f*)Vp, cm, rm,
        cost, (long)PX, (long)NIMG*PX,
        X1, (long)C*PX, (long)PX,
        gamma);

    // pass 2: x = X1 ([n][c][h][w]); final out layout [c][n][h][w]
    qkv_kernel<<<qkv_blocks, 256, 0, stream>>>(
        X1, (long)C*PX, (long)PX,
        q_w, q_b, k_w, k_b, v_w, v_b, Qp, Kp, Vp);
    stats_kernel<<<NIMG, 192, 0, stream>>>(Kp, cm, rm);
    attn_kernel<<<attn_blocks, 384, 0, stream>>>(
        Qp, Kp, (const v4f*)Vp, cm, rm,
        X1, (long)C*PX, (long)PX,
        out, (long)PX, (long)NIMG*PX,
        gamma);
}